// Round 10
// baseline (98.052 us; speedup 1.0000x reference)
//
#include <hip/hip_runtime.h>
#include <cstdint>
#include <cstddef>

typedef __attribute__((ext_vector_type(8))) short short8v;
typedef __attribute__((ext_vector_type(4))) unsigned uint4v;
typedef __attribute__((ext_vector_type(4))) float floatx4;

#define LIN 568   // weight row length: 1 + 9*63

__device__ __forceinline__ short f32_to_bf16(float f) {
  unsigned u = __builtin_bit_cast(unsigned, f);
  u += 0x7fffu + ((u >> 16) & 1u);   // RNE (inputs finite)
  return (short)(u >> 16);
}
__device__ __forceinline__ float bf16_to_f32(short s) {
  return __builtin_bit_cast(float, ((unsigned)(unsigned short)s) << 16);
}
// Packed RNE f32->bf16 (2 values / instruction), bitwise-identical to manual RNE.
__device__ __forceinline__ unsigned cvt_pk_bf16(float lo, float hi) {
  unsigned r;
  asm("v_cvt_pk_bf16_f32 %0, %1, %2" : "=v"(r) : "v"(lo), "v"(hi));
  return r;
}
// Cross-lane add via DPP (pure VALU, no ds op).
template<int CTRL>
__device__ __forceinline__ float dpp_add(float v) {
  int y = __builtin_amdgcn_update_dpp(0, __builtin_bit_cast(int, v), CTRL, 0xF, 0xF, true);
  return v + __builtin_bit_cast(float, y);
}

// Pack weight into MFMA-B-fragment-major order (bf16):
//   wfragg[step*2048 + nb*512 + lane*8 + j]
//     = W[n = nb*16 + (lane&15)][k = tap*64 + half*32 + (lane>>4)*8 + j]
// step = tap*2 + half; c==0 column zeroed (time feature is rank-1 epilogue).
__global__ void prep_weight(const float* __restrict__ w, short* __restrict__ wfragg) {
  int i = blockIdx.x * 256 + threadIdx.x;   // 0 .. 36863
  if (i >= 9 * 2 * 4 * 64 * 8) return;
  int j    = i & 7;
  int lane = (i >> 3) & 63;
  int nb   = (i >> 9) & 3;
  int half = (i >> 11) & 1;
  int tap  = i >> 12;
  int n = nb * 16 + (lane & 15);
  int c = half * 32 + ((lane >> 4) << 3) + j;
  float v = (c == 0) ? 0.0f : w[n * LIN + 1 + tap * 63 + (c - 1)];
  wfragg[i] = f32_to_bf16(v);
}

// R8 champion structure, n-SPLIT: 512 threads = 8 waves; wave (rr=wv>>1, nh=wv&1)
// computes row rr, out-ch half nh (4 m-blocks x 2 n-blocks, 144 MFMA/wave).
// Per-wave B-stream and MFMA path HALVE; A-reads and staging unchanged; total
// traffic unchanged; waves/SIMD 2->4. Lorentz sum now spans the nh-pair ->
// LDS partial-sum exchange (+1 barrier). Everything else byte-equal to R8.
__launch_bounds__(512, 2)
__global__ void lconv_main(const float* __restrict__ x, const float* __restrict__ w,
                           const float* __restrict__ bias, const short* __restrict__ wfragg,
                           float* __restrict__ out) {
  // 66560 B: short xt[6*66*72] (57024 B) during compute, then aliased as
  // float ostg[4][4160] for the store-staging epilogue.
  __shared__ __align__(16) char shmem[4 * 4160 * 4];
  __shared__ float tres_s[4 * 64];    // per-row time-feature (dup-written by nh pair)
  __shared__ float pss[2][4][64];     // [nh][row][pcol] partial Lorentz sums
  short* xt = (short*)shmem;

  const int tid = threadIdx.x;
  const int bb = blockIdx.x >> 4;          // batch 0..31
  const int h0 = (blockIdx.x & 15) << 2;   // first output row of 4-row strip
  const float* xb = x + (size_t)bb * (64 * 64 * 64);

  const int lane = tid & 63;
  const int l15 = lane & 15;
  const int q = lane >> 4;
  const int wv = tid >> 6;    // wave 0..7
  const int rr = wv >> 1;     // strip row 0..3
  const int nh = wv & 1;      // out-channel half (ch 0..31 / 32..63)

  // ---- phase-1 staging loads (rows 0..3), issue-early ----
  float4 s0[6], s1[6];
#pragma unroll
  for (int i = 0; i < 4; ++i) {
    int idx = i * 512 + tid;       // 0..2047 : rows 0..3 x 64 cols x 8 ch8-groups
    int row = idx >> 9;
    int rem = idx & 511;
    int col = rem >> 3;
    int ch8 = (rem & 7) << 3;
    int h = h0 - 1 + row;
    s0[i] = {0.f, 0.f, 0.f, 0.f};
    s1[i] = {0.f, 0.f, 0.f, 0.f};
    if ((unsigned)h < 64u) {
      const float* p = xb + ((h * 64 + col) * 64 + ch8);
      s0[i] = *(const float4*)p;
      s1[i] = *(const float4*)(p + 4);
    }
  }

  // ---- B fragments for steps 0..2 (this wave's n-half only) + constants ----
  const short* wfl = wfragg + lane * 8;
  short8v b0[2], b1[2], b2[2];
#pragma unroll
  for (int nbl = 0; nbl < 2; ++nbl) {
    const short* base = wfl + (nh * 2 + nbl) * 512;
    b0[nbl] = *(const short8v*)(base + 0 * 2048);
    b1[nbl] = *(const short8v*)(base + 1 * 2048);
    b2[nbl] = *(const short8v*)(base + 2 * 2048);
  }
  float bj[2], w0j[2];
#pragma unroll
  for (int nbl = 0; nbl < 2; ++nbl) {
    int n = (nh * 2 + nbl) * 16 + l15;
    bj[nbl] = bias[n];
    w0j[nbl] = w[n * LIN];   // weight[:,0] fp32
  }

  // ---- phase-1 convert+write: LDS rows 0..3 ----
#pragma unroll
  for (int i = 0; i < 4; ++i) {
    int idx = i * 512 + tid;
    int row = idx >> 9;
    int rem = idx & 511;
    int col = rem >> 3;
    int ch8 = (rem & 7) << 3;
    uint4v o;
    o[0] = cvt_pk_bf16(s0[i].x, s0[i].y);
    o[1] = cvt_pk_bf16(s0[i].z, s0[i].w);
    o[2] = cvt_pk_bf16(s1[i].x, s1[i].y);
    o[3] = cvt_pk_bf16(s1[i].z, s1[i].w);
    *(uint4v*)&xt[(row * 66 + col + 1) * 72 + ch8] = o;
  }
  if (tid < 64) {   // pads for rows 0..3, cols 0 and 65
    int r = tid >> 4;
    int cc = (tid >> 3) & 1;
    int ch8 = (tid & 7) << 3;
    short8v z = {0, 0, 0, 0, 0, 0, 0, 0};
    *(short8v*)&xt[(r * 66 + cc * 65) * 72 + ch8] = z;
  }
  __syncthreads();   // rows 0..3 visible

  // ---- phase-2 staging loads (rows 4..5): issued here, written after steps 0..5 ----
#pragma unroll
  for (int i = 4; i < 6; ++i) {
    int idx = i * 512 + tid;       // 2048..3071 : rows 4..5
    int row = idx >> 9;
    int rem = idx & 511;
    int col = rem >> 3;
    int ch8 = (rem & 7) << 3;
    int h = h0 - 1 + row;
    s0[i] = {0.f, 0.f, 0.f, 0.f};
    s1[i] = {0.f, 0.f, 0.f, 0.f};
    if ((unsigned)h < 64u) {
      const float* p = xb + ((h * 64 + col) * 64 + ch8);
      s0[i] = *(const float4*)p;
      s1[i] = *(const float4*)(p + 4);
    }
  }

  floatx4 acc[4][2];
#pragma unroll
  for (int mb = 0; mb < 4; ++mb)
#pragma unroll
    for (int nbl = 0; nbl < 2; ++nbl) acc[mb][nbl] = floatx4{0.f, 0.f, 0.f, 0.f};

  auto do_step = [&](int step) {
    const int tap = step >> 1, half = step & 1;
    const int kh = tap / 3, kw = tap % 3;

    short8v bn[2];
    if (step + 3 < 18) {
#pragma unroll
      for (int nbl = 0; nbl < 2; ++nbl)
        bn[nbl] = *(const short8v*)(wfl + (step + 3) * 2048 + (nh * 2 + nbl) * 512);
    }

    const short* ab = &xt[((rr + kh) * 66 + kw + l15) * 72 + half * 32 + q * 8];
    short8v a[4];
#pragma unroll
    for (int mb = 0; mb < 4; ++mb)
      a[mb] = *(const short8v*)(ab + mb * 16 * 72);

#pragma unroll
    for (int mb = 0; mb < 4; ++mb) {
#pragma unroll
      for (int nbl = 0; nbl < 2; ++nbl)
        acc[mb][nbl] = __builtin_amdgcn_mfma_f32_16x16x32_bf16(a[mb], b0[nbl], acc[mb][nbl], 0, 0, 0);
    }
#pragma unroll
    for (int nbl = 0; nbl < 2; ++nbl) { b0[nbl] = b1[nbl]; b1[nbl] = b2[nbl]; b2[nbl] = bn[nbl]; }
  };

  // kh=0 taps (steps 0..5): rows 0..3 only; phase-2 loads in flight underneath
#pragma unroll
  for (int step = 0; step < 6; ++step) do_step(step);

  // ---- phase-2 write-late: LDS rows 4..5 ----
#pragma unroll
  for (int i = 4; i < 6; ++i) {
    int idx = i * 512 + tid;
    int row = idx >> 9;
    int rem = idx & 511;
    int col = rem >> 3;
    int ch8 = (rem & 7) << 3;
    uint4v o;
    o[0] = cvt_pk_bf16(s0[i].x, s0[i].y);
    o[1] = cvt_pk_bf16(s0[i].z, s0[i].w);
    o[2] = cvt_pk_bf16(s1[i].x, s1[i].y);
    o[3] = cvt_pk_bf16(s1[i].z, s1[i].w);
    *(uint4v*)&xt[(row * 66 + col + 1) * 72 + ch8] = o;
  }
  if (tid < 32) {   // pads for rows 4..5
    int r = 4 + (tid >> 4);
    int cc = (tid >> 3) & 1;
    int ch8 = (tid & 7) << 3;
    short8v z = {0, 0, 0, 0, 0, 0, 0, 0};
    *(short8v*)&xt[(r * 66 + cc * 65) * 72 + ch8] = z;
  }
  __syncthreads();   // rows 4..5 visible

#pragma unroll
  for (int step = 6; step < 18; ++step) do_step(step);

  // ---- per-pixel time feature (both nh waves compute identically for row rr) ----
  {
    float ss = 0.f;
#pragma unroll
    for (int dh = 0; dh < 3; ++dh)
#pragma unroll
      for (int dw = 0; dw < 3; ++dw) {
        float tv = bf16_to_f32(xt[((rr + dh) * 66 + lane + dw) * 72]);
        tv = fmaxf(tv, 1.0f);
        ss += tv * tv;
      }
    tres_s[rr * 64 + lane] = sqrtf(ss - 8.0f);   // same value from both nh waves
  }

  // ---- epilogue pass 1: v = acc + bias + rank-1; partial Lorentz sums -> LDS ----
#pragma unroll
  for (int mb = 0; mb < 4; ++mb) {
    float4 t4 = *(const float4*)&tres_s[rr * 64 + mb * 16 + q * 4];
#pragma unroll
    for (int r = 0; r < 4; ++r) {
      int pcol = mb * 16 + q * 4 + r;
      float tr = t4[r];
      float v0 = acc[mb][0][r] + bj[0] + tr * w0j[0];
      float v1 = acc[mb][1][r] + bj[1] + tr * w0j[1];
      acc[mb][0][r] = v0;   // keep for pass 2 (acc storage reused)
      acc[mb][1][r] = v1;
      float ss = v0 * v0 + v1 * v1;
      ss = dpp_add<0xB1>(ss);    // + lane^1
      ss = dpp_add<0x4E>(ss);    // + lane^2
      ss = dpp_add<0x141>(ss);   // + mirror-8
      ss = dpp_add<0x140>(ss);   // + mirror-16 -> sum of this wave's 32 channels
      if (l15 == 0) pss[nh][rr][pcol] = ss;
    }
  }

  __syncthreads();   // pss visible + last xt read done -> safe to alias as ostg

  // ---- epilogue pass 2: scatter to LDS row image ----
  float* ostg = (float*)shmem + rr * 4160;   // row image: 64 px x 65 ch
#pragma unroll
  for (int mb = 0; mb < 4; ++mb) {
#pragma unroll
    for (int r = 0; r < 4; ++r) {
      int pcol = mb * 16 + q * 4 + r;
      float* pb = ostg + pcol * 65;
      if (nh == 0) {
        if (l15 == 0) pb[0] = sqrtf(pss[0][rr][pcol] + pss[1][rr][pcol] + 1.0f);
        pb[1 + l15]  = acc[mb][0][r];
        pb[17 + l15] = acc[mb][1][r];
      } else {
        pb[33 + l15] = acc[mb][0][r];
        pb[49 + l15] = acc[mb][1][r];
      }
    }
  }

  __syncthreads();   // full row images visible

  // ---- coalesced flush: each wave streams half of its row (2080 floats) ----
  {
    float* orow = out + (size_t)((bb * 64 + h0 + rr) * 64) * 65;
    const float* lrow = (const float*)shmem + rr * 4160;
    int base = nh * 2080;
#pragma unroll
    for (int it = 0; it < 8; ++it) {
      int off = base + it * 256 + lane * 4;
      *(float4*)(orow + off) = *(const float4*)(lrow + off);
    }
    if (lane < 8) {   // remainder: 2080 - 2048 = 32 floats
      int off = base + 2048 + lane * 4;
      *(float4*)(orow + off) = *(const float4*)(lrow + off);
    }
  }
}

extern "C" void kernel_launch(void* const* d_in, const int* in_sizes, int n_in,
                              void* d_out, int out_size, void* d_ws, size_t ws_size,
                              hipStream_t stream) {
  const float* x = (const float*)d_in[0];
  const float* w = (const float*)d_in[1];
  const float* b = (const float*)d_in[2];
  float* out = (float*)d_out;
  short* wfragg = (short*)d_ws;   // 73728 B fragment-packed bf16 weight

  prep_weight<<<144, 256, 0, stream>>>(w, wfragg);
  lconv_main<<<32 * 16, 512, 0, stream>>>(x, w, b, wfragg, out);
}